// Round 7
// baseline (68.106 us; speedup 1.0000x reference)
//
#include <hip/hip_runtime.h>
#include <math.h>

#define B_N 2048
#define DIM 32
#define K_N 10
#define NP  528          // sorted pairs (i<=j)
#define NCOLP 640        // padded column count (5 tiles x 128)
#define TILE 128
#define NT 5
#define NBLK (NT*NT*K_N)
#define NR 2368          // padded sample rows: 2048 + 10*32
#define NPAD (NR - B_N)  // 320

typedef __attribute__((ext_vector_type(8))) short bf16x8;   // 8 bf16 = 4 VGPRs
typedef __attribute__((ext_vector_type(4))) float f32x4;    // mfma 16x16 accum

// ---- ws layout (4-byte words) ----
#define WS_CW     0               // cw[10]
#define WS_OFFP   16              // offp[11] (padded exclusive scan)
#define WS_LOSS   48
#define WS_CTR    49
#define WS_DIFFC  2112            // NR*32 floats = 75776 words (16B aligned)
#define WS_VT     (2112 + 75776)  // ushort[640*NR] (16B aligned)

__device__ __forceinline__ float c2f(float x) {
  float r = sqrtf(fabsf(x) + 0.25f) - 0.5f;
  return (x >= 0.f) ? r : -r;
}
__device__ __forceinline__ float c3f(float x) {
  float r = cbrtf(fabsf(x) + 0.19245008973f) - 0.57735026919f;
  return (x >= 0.f) ? r : -r;
}
__device__ __forceinline__ float c4f(float x) {
  float r = sqrtf(sqrtf(fabsf(x) + 0.15749013123f)) - 0.62996052494f;
  return (x >= 0.f) ? r : -r;
}
#define T4C1 (sqrtf(sqrtf(1.f + 0.15749013123f)) - 0.62996052494f)

// col -> (u,v) with d[32]=1 (ones), d[33]=0 (pad)
__device__ __forceinline__ void decode_col(int g, int& u, int& v) {
  if (g < NP) {
    int j = (int)((sqrtf(8.f * (float)g + 1.f) - 1.f) * 0.5f);
    while (j * (j + 1) / 2 > g) --j;
    while ((j + 1) * (j + 2) / 2 <= g) ++j;
    u = g - j * (j + 1) / 2; v = j;
  } else if (g < 560) { u = g - NP; v = 32; }
  else if (g == 560)  { u = 32; v = 32; }
  else                { u = 33; v = 33; }
}

// fp32 -> bf16 bits, round-to-nearest-even
__device__ __forceinline__ unsigned short f2bf(float f) {
  unsigned u = __builtin_bit_cast(unsigned, f);
  return (unsigned short)((u + 0x7FFFu + ((u >> 16) & 1u)) >> 16);
}

// ---- kernel 1: fused init + assign + scan + scatter + pad-zero (1 block) ----
__global__ __launch_bounds__(1024) void k_prep(const float* __restrict__ emb,
                                               const float* __restrict__ cen,
                                               const float* __restrict__ lg,
                                               int* __restrict__ cw_g,
                                               int* __restrict__ offp_g,
                                               float* __restrict__ diffc,
                                               float* __restrict__ lossAcc,
                                               int* __restrict__ ctr) {
  __shared__ int scw[K_N], scur[K_N], soff[K_N + 1];
  __shared__ short skb[B_N];
  const int t = threadIdx.x;
  if (t < K_N) { scw[t] = 0; scur[t] = 0; }
  __syncthreads();

  // argmax + ballot histogram (2 uniform iterations)
  #pragma unroll
  for (int it = 0; it < B_N / 1024; ++it) {
    int b = t + it * 1024;
    const float* l = lg + (size_t)b * K_N;
    float best = l[0]; int bi = 0;
    #pragma unroll
    for (int k = 1; k < K_N; ++k) { float v = l[k]; if (v > best) { best = v; bi = k; } }
    skb[b] = (short)bi;
    #pragma unroll
    for (int k = 0; k < K_N; ++k) {
      unsigned long long m = __ballot(bi == k);
      if ((t & 63) == 0 && m) atomicAdd(&scw[k], (int)__popcll(m));
    }
  }
  __syncthreads();

  if (t == 0) {
    int s = 0;
    #pragma unroll
    for (int k = 0; k < K_N; ++k) { soff[k] = s; s += (scw[k] + 31) & ~31; }
    soff[K_N] = s;
    *lossAcc = 0.f; *ctr = 0;
  }
  __syncthreads();
  if (t < K_N) { cw_g[t] = scw[t]; offp_g[t] = soff[t]; }

  // compact scatter
  #pragma unroll
  for (int it = 0; it < B_N / 1024; ++it) {
    int b = t + it * 1024;
    int k = skb[b];
    int pos = soff[k] + atomicAdd(&scur[k], 1);
    const float4* e4 = reinterpret_cast<const float4*>(emb + (size_t)b * DIM);
    const float4* c4p = reinterpret_cast<const float4*>(cen + (size_t)k * DIM);
    float4* o4 = reinterpret_cast<float4*>(diffc + (size_t)pos * DIM);
    #pragma unroll
    for (int q = 0; q < 8; ++q) {
      float4 e = e4[q], c = c4p[q];
      o4[q] = make_float4(e.x - c.x, e.y - c.y, e.z - c.z, e.w - c.w);
    }
  }

  // zero the NPAD pad/tail rows
  if (t < NPAD) {
    int p = t;
    int cp = 0, row = -1;
    #pragma unroll
    for (int kk = 0; kk < K_N; ++kk) {
      int nb = scw[kk];
      int pad = ((nb + 31) & ~31) - nb;
      if (row < 0 && p < cp + pad) row = soff[kk] + nb + (p - cp);
      cp += pad;
    }
    if (row < 0) row = soff[K_N] + (p - cp);
    if (row < NR) {
      float4* o4 = reinterpret_cast<float4*>(diffc + (size_t)row * DIM);
      #pragma unroll
      for (int q = 0; q < 8; ++q) o4[q] = make_float4(0.f, 0.f, 0.f, 0.f);
    }
  }
}

// ---- kernel 2: expand diffc -> Vt[640 cols][NR samples] in bf16 (transposed) ----
__global__ __launch_bounds__(256) void k_expand(const float* __restrict__ diffc,
                                                unsigned short* __restrict__ Vt) {
  __shared__ float sd[16][36];
  const int t = threadIdx.x;
  const int base = blockIdx.x * 16;
  if (t < 128) {
    int row = t >> 3, d4 = t & 7;
    float4 v = *reinterpret_cast<const float4*>(&diffc[(size_t)(base + row) * DIM + d4 * 4]);
    *reinterpret_cast<float4*>(&sd[row][d4 * 4]) = v;
    if (d4 == 0) { sd[row][32] = 1.f; sd[row][33] = 0.f; }
  }
  __syncthreads();
  for (int c = t; c < NCOLP; c += 256) {
    int u, v; decode_col(c, u, v);
    unsigned short* dst = Vt + (size_t)c * NR + base;
    #pragma unroll
    for (int r8 = 0; r8 < 2; ++r8) {
      bf16x8 pack;
      #pragma unroll
      for (int e = 0; e < 8; ++e)
        pack[e] = (short)f2bf(sd[r8 * 8 + e][u] * sd[r8 * 8 + e][v]);
      *reinterpret_cast<bf16x8*>(dst + r8 * 8) = pack;
    }
  }
}

// ---- kernel 3: MFMA Gram + fused loss (validated r6, absmax 0) ----
__global__ __launch_bounds__(256) void k_main(const unsigned short* __restrict__ Vt,
                                              const int* __restrict__ cw,
                                              const int* __restrict__ offp,
                                              float* __restrict__ lossAcc,
                                              int* __restrict__ ctr,
                                              float* __restrict__ out) {
  const int k  = blockIdx.z;
  const int Pt = blockIdx.y, Qt = blockIdx.x;
  const int nb = cw[k];
  const int base = offp[k];
  const int nbp = (nb + 31) & ~31;
  const int t = threadIdx.x;
  const int w = t >> 6, l = t & 63;
  const int wr = w >> 1, wc = w & 1;
  const int lr = l & 15, kg = l >> 4;

  __shared__ unsigned char tI0[NCOLP], tI1[NCOLP];
  __shared__ float sred[4];
  for (int c = t; c < NCOLP; c += 256) {
    int u, v; decode_col(c, u, v);
    tI0[c] = (unsigned char)u; tI1[c] = (unsigned char)v;
  }

  const int pb = Pt * TILE + wr * 64;   // wave's P quadrant base
  const int qb = Qt * TILE + wc * 64;   // wave's Q quadrant base

  f32x4 acc[4][4];
  {
    f32x4 z = {0.f, 0.f, 0.f, 0.f};
    #pragma unroll
    for (int a = 0; a < 4; ++a)
      #pragma unroll
      for (int c = 0; c < 4; ++c) acc[a][c] = z;
  }

  if (nbp > 0) {
    // frag: lane holds col = pb/qb + f*16 + lr, samples k0 + kg*8 .. +7
    const unsigned short* Ap = Vt + (size_t)(pb + lr) * NR + base + kg * 8;
    const unsigned short* Bp = Vt + (size_t)(qb + lr) * NR + base + kg * 8;
    bf16x8 a[4], b[4];
    #pragma unroll
    for (int f = 0; f < 4; ++f) {
      a[f] = *reinterpret_cast<const bf16x8*>(Ap + (size_t)(f * 16) * NR);
      b[f] = *reinterpret_cast<const bf16x8*>(Bp + (size_t)(f * 16) * NR);
    }
    for (int k0 = 32; k0 <= nbp; k0 += 32) {
      bf16x8 an[4], bn[4];
      const bool more = (k0 < nbp);
      if (more) {                       // prefetch next K-chunk during MFMA burst
        #pragma unroll
        for (int f = 0; f < 4; ++f) {
          an[f] = *reinterpret_cast<const bf16x8*>(Ap + (size_t)(f * 16) * NR + k0);
          bn[f] = *reinterpret_cast<const bf16x8*>(Bp + (size_t)(f * 16) * NR + k0);
        }
      }
      #pragma unroll
      for (int fa = 0; fa < 4; ++fa)
        #pragma unroll
        for (int fc = 0; fc < 4; ++fc)
          acc[fa][fc] = __builtin_amdgcn_mfma_f32_16x16x32_bf16(a[fa], b[fc], acc[fa][fc], 0, 0, 0);
      if (more) {
        #pragma unroll
        for (int f = 0; f < 4; ++f) { a[f] = an[f]; b[f] = bn[f]; }
      }
    }
  }
  __syncthreads();   // tI tables ready for epilogue

  // ---- fused epilogue ----
  // C/D layout (m89-verified): Q(col) = lane&15, P(row) = (lane>>4)*4 + reg
  const float inv_cnt = 1.f / ((float)nb + 1e-7f);
  float sum = 0.f;
  #pragma unroll
  for (int fa = 0; fa < 4; ++fa) {
    #pragma unroll
    for (int r = 0; r < 4; ++r) {
      const int P = pb + fa * 16 + kg * 4 + r;
      const int i = tI0[P], j = tI1[P];
      #pragma unroll
      for (int fc = 0; fc < 4; ++fc) {
        const int Q = qb + fc * 16 + lr;
        const int li = tI0[Q], mi = tI1[Q];
        const float g = acc[fa][fc][r];
        if (P < NP) {
          if (Q < NP) {
            int s0 = min(i, li), x1 = max(i, li), x2 = min(j, mi), s3 = max(j, mi);
            int s1 = min(x1, x2), s2 = max(x1, x2);
            bool e01 = (s0 == s1), e12 = (s1 == s2), e23 = (s2 == s3);
            float wgt, tgt = 0.f;
            if (e01 && e12 && e23)                 wgt = 0.f;
            else if (e01 && e23)                   { wgt = 2.f / 9.f; tgt = T4C1; }
            else if ((e01 && e12) || (e12 && e23)) wgt = 0.25f;
            else if (e01 || e12 || e23)            wgt = 5.f / 24.f;
            else                                   wgt = 1.f / 6.f;
            float d = c4f(g) - tgt;
            sum += 0.125f * wgt * d * d;
          } else if (Q < 560) {
            if (Q - NP >= j) { float d = c3f(g); sum += 0.25f * d * d; }
          } else if (Q == 560) {
            if (i < j) { float d = c2f(g * inv_cnt); sum += 0.5f * d * d; }
          }
        } else if (P < 560 && Q == 560) {
          float m1 = g * inv_cnt;
          sum += m1 * m1;
        }
      }
    }
  }

  #pragma unroll
  for (int off = 32; off > 0; off >>= 1) sum += __shfl_down(sum, off, 64);
  if ((t & 63) == 0) sred[t >> 6] = sum;
  __syncthreads();
  if (t == 0) {
    float s = sred[0] + sred[1] + sred[2] + sred[3];
    atomicAdd(lossAcc, s * ((float)nb * (1.f / (float)B_N)));
    __threadfence();
    if (atomicAdd(ctr, 1) == NBLK - 1) out[0] = atomicAdd(lossAcc, 0.f);
  }
}

extern "C" void kernel_launch(void* const* d_in, const int* in_sizes, int n_in,
                              void* d_out, int out_size, void* d_ws, size_t ws_size,
                              hipStream_t stream) {
  const float* emb = (const float*)d_in[0];
  const float* cen = (const float*)d_in[1];
  const float* lg  = (const float*)d_in[2];
  float* out = (float*)d_out;

  int*   wsi    = (int*)d_ws;
  float* wsf    = (float*)d_ws;
  int*   cw     = wsi + WS_CW;
  int*   offp   = wsi + WS_OFFP;
  float* lossA  = wsf + WS_LOSS;
  int*   ctr    = wsi + WS_CTR;
  float* diffc  = wsf + WS_DIFFC;
  unsigned short* Vt = (unsigned short*)(wsf + WS_VT);

  k_prep  <<<1, 1024, 0, stream>>>(emb, cen, lg, cw, offp, diffc, lossA, ctr);
  k_expand<<<NR / 16, 256, 0, stream>>>(diffc, Vt);
  k_main  <<<dim3(NT, NT, K_N), 256, 0, stream>>>(Vt, cw, offp, lossA, ctr, out);
}

// Round 8
// 63.440 us; speedup vs baseline: 1.0736x; 1.0736x over previous
//
#include <hip/hip_runtime.h>
#include <math.h>

#define B_N 2048
#define DIM 32
#define K_N 10
#define NP  528          // sorted pairs (i<=j)
#define NCOLP 640        // padded column count (5 tiles x 128)
#define TILE 128
#define NT 5
#define NBLK (NT*NT*K_N)
#define NR 2368          // padded sample rows: 2048 + 10*32
#define NPAD (NR - B_N)  // 320

typedef __attribute__((ext_vector_type(8))) short bf16x8;   // 8 bf16 = 4 VGPRs
typedef __attribute__((ext_vector_type(4))) float f32x4;    // mfma 16x16 accum

// ---- ws layout (4-byte words) ----
#define WS_CW     0               // cw[10]
#define WS_OFFP   16              // offp[11] (padded exclusive scan)
#define WS_LOSS   48
#define WS_CTR    49
#define WS_DIFFC  2112            // NR*32 floats = 75776 words (16B aligned)
#define WS_VT     (2112 + 75776)  // ushort[(NR/8)][NCOLP][8] (16B aligned)

__device__ __forceinline__ float c2f(float x) {
  float r = sqrtf(fabsf(x) + 0.25f) - 0.5f;
  return (x >= 0.f) ? r : -r;
}
__device__ __forceinline__ float c3f(float x) {
  float r = cbrtf(fabsf(x) + 0.19245008973f) - 0.57735026919f;
  return (x >= 0.f) ? r : -r;
}
__device__ __forceinline__ float c4f(float x) {
  float r = sqrtf(sqrtf(fabsf(x) + 0.15749013123f)) - 0.62996052494f;
  return (x >= 0.f) ? r : -r;
}
#define T4C1 (sqrtf(sqrtf(1.f + 0.15749013123f)) - 0.62996052494f)

// col -> (u,v) with d[32]=1 (ones), d[33]=0 (pad)
__device__ __forceinline__ void decode_col(int g, int& u, int& v) {
  if (g < NP) {
    int j = (int)((sqrtf(8.f * (float)g + 1.f) - 1.f) * 0.5f);
    while (j * (j + 1) / 2 > g) --j;
    while ((j + 1) * (j + 2) / 2 <= g) ++j;
    u = g - j * (j + 1) / 2; v = j;
  } else if (g < 560) { u = g - NP; v = 32; }
  else if (g == 560)  { u = 32; v = 32; }
  else                { u = 33; v = 33; }
}

// fp32 -> bf16 bits, round-to-nearest-even
__device__ __forceinline__ unsigned short f2bf(float f) {
  unsigned u = __builtin_bit_cast(unsigned, f);
  return (unsigned short)((u + 0x7FFFu + ((u >> 16) & 1u)) >> 16);
}

// ---- kernel 1: fused init + assign + scan + scatter + pad-zero (1 block) ----
__global__ __launch_bounds__(1024) void k_prep(const float* __restrict__ emb,
                                               const float* __restrict__ cen,
                                               const float* __restrict__ lg,
                                               int* __restrict__ cw_g,
                                               int* __restrict__ offp_g,
                                               float* __restrict__ diffc,
                                               float* __restrict__ lossAcc,
                                               int* __restrict__ ctr) {
  __shared__ int scw[K_N], scur[K_N], soff[K_N + 1];
  __shared__ short skb[B_N];
  const int t = threadIdx.x;
  if (t < K_N) { scw[t] = 0; scur[t] = 0; }
  __syncthreads();

  // argmax + ballot histogram (2 uniform iterations)
  #pragma unroll
  for (int it = 0; it < B_N / 1024; ++it) {
    int b = t + it * 1024;
    const float* l = lg + (size_t)b * K_N;
    float best = l[0]; int bi = 0;
    #pragma unroll
    for (int k = 1; k < K_N; ++k) { float v = l[k]; if (v > best) { best = v; bi = k; } }
    skb[b] = (short)bi;
    #pragma unroll
    for (int k = 0; k < K_N; ++k) {
      unsigned long long m = __ballot(bi == k);
      if ((t & 63) == 0 && m) atomicAdd(&scw[k], (int)__popcll(m));
    }
  }
  __syncthreads();

  if (t == 0) {
    int s = 0;
    #pragma unroll
    for (int k = 0; k < K_N; ++k) { soff[k] = s; s += (scw[k] + 31) & ~31; }
    soff[K_N] = s;
    *lossAcc = 0.f; *ctr = 0;
  }
  __syncthreads();
  if (t < K_N) { cw_g[t] = scw[t]; offp_g[t] = soff[t]; }

  // compact scatter
  #pragma unroll
  for (int it = 0; it < B_N / 1024; ++it) {
    int b = t + it * 1024;
    int k = skb[b];
    int pos = soff[k] + atomicAdd(&scur[k], 1);
    const float4* e4 = reinterpret_cast<const float4*>(emb + (size_t)b * DIM);
    const float4* c4p = reinterpret_cast<const float4*>(cen + (size_t)k * DIM);
    float4* o4 = reinterpret_cast<float4*>(diffc + (size_t)pos * DIM);
    #pragma unroll
    for (int q = 0; q < 8; ++q) {
      float4 e = e4[q], c = c4p[q];
      o4[q] = make_float4(e.x - c.x, e.y - c.y, e.z - c.z, e.w - c.w);
    }
  }

  // zero the NPAD pad/tail rows
  if (t < NPAD) {
    int p = t;
    int cp = 0, row = -1;
    #pragma unroll
    for (int kk = 0; kk < K_N; ++kk) {
      int nb = scw[kk];
      int pad = ((nb + 31) & ~31) - nb;
      if (row < 0 && p < cp + pad) row = soff[kk] + nb + (p - cp);
      cp += pad;
    }
    if (row < 0) row = soff[K_N] + (p - cp);
    if (row < NR) {
      float4* o4 = reinterpret_cast<float4*>(diffc + (size_t)row * DIM);
      #pragma unroll
      for (int q = 0; q < 8; ++q) o4[q] = make_float4(0.f, 0.f, 0.f, 0.f);
    }
  }
}

// ---- kernel 2: expand diffc -> Vt[chunk][col][8] in bf16 (sample-tiled) ----
__global__ __launch_bounds__(256) void k_expand(const float* __restrict__ diffc,
                                                unsigned short* __restrict__ Vt) {
  __shared__ float sd[16][36];
  const int t = threadIdx.x;
  const int base = blockIdx.x * 16;      // covers chunks 2b, 2b+1
  const int chunk0 = blockIdx.x * 2;
  if (t < 128) {
    int row = t >> 3, d4 = t & 7;
    float4 v = *reinterpret_cast<const float4*>(&diffc[(size_t)(base + row) * DIM + d4 * 4]);
    *reinterpret_cast<float4*>(&sd[row][d4 * 4]) = v;
    if (d4 == 0) { sd[row][32] = 1.f; sd[row][33] = 0.f; }
  }
  __syncthreads();
  for (int c = t; c < NCOLP; c += 256) {
    int u, v; decode_col(c, u, v);
    #pragma unroll
    for (int r8 = 0; r8 < 2; ++r8) {
      bf16x8 pack;
      #pragma unroll
      for (int e = 0; e < 8; ++e)
        pack[e] = (short)f2bf(sd[r8 * 8 + e][u] * sd[r8 * 8 + e][v]);
      // coalesced: consecutive threads (cols) -> consecutive 16B
      *reinterpret_cast<bf16x8*>(Vt + ((size_t)(chunk0 + r8) * NCOLP + c) * 8) = pack;
    }
  }
}

// ---- kernel 3: MFMA Gram + fused loss (algebra validated r2/r5/r6, absmax 0) ----
__global__ __launch_bounds__(256) void k_main(const unsigned short* __restrict__ Vt,
                                              const int* __restrict__ cw,
                                              const int* __restrict__ offp,
                                              float* __restrict__ lossAcc,
                                              int* __restrict__ ctr,
                                              float* __restrict__ out) {
  const int k  = blockIdx.z;
  const int Pt = blockIdx.y, Qt = blockIdx.x;
  const int nb = cw[k];
  const int base = offp[k];              // multiple of 32
  const int nbp = (nb + 31) & ~31;
  const int t = threadIdx.x;
  const int w = t >> 6, l = t & 63;
  const int wr = w >> 1, wc = w & 1;
  const int lr = l & 15, kg = l >> 4;

  __shared__ unsigned char tI0[NCOLP], tI1[NCOLP];
  __shared__ float sred[4];
  for (int c = t; c < NCOLP; c += 256) {
    int u, v; decode_col(c, u, v);
    tI0[c] = (unsigned char)u; tI1[c] = (unsigned char)v;
  }

  const int pb = Pt * TILE + wr * 64;   // wave's P quadrant base
  const int qb = Qt * TILE + wc * 64;   // wave's Q quadrant base

  f32x4 acc[4][4];
  {
    f32x4 z = {0.f, 0.f, 0.f, 0.f};
    #pragma unroll
    for (int a = 0; a < 4; ++a)
      #pragma unroll
      for (int c = 0; c < 4; ++c) acc[a][c] = z;
  }

  if (nbp > 0) {
    // tiled layout: fragment (col = pb + f*16 + lr, chunk = base/8 + kg) is
    // 16B at ((chunk)*NCOLP + col)*8; lanes 0..15 -> contiguous 256B.
    const int cbase = base >> 3;
    const unsigned short* Ap = Vt + ((size_t)(cbase + kg) * NCOLP + pb + lr * 1) * 8;
    const unsigned short* Bp = Vt + ((size_t)(cbase + kg) * NCOLP + qb + lr * 1) * 8;
    // advancing 32 samples = 4 chunks = +32*NCOLP ushorts -> offset k0*NCOLP
    bf16x8 a[4], b[4];
    #pragma unroll
    for (int f = 0; f < 4; ++f) {
      a[f] = *reinterpret_cast<const bf16x8*>(Ap + (size_t)(f * 16) * 8);
      b[f] = *reinterpret_cast<const bf16x8*>(Bp + (size_t)(f * 16) * 8);
    }
    for (int k0 = 32; k0 <= nbp; k0 += 32) {
      bf16x8 an[4], bn[4];
      const bool more = (k0 < nbp);
      if (more) {                       // prefetch next K-chunk during MFMA burst
        #pragma unroll
        for (int f = 0; f < 4; ++f) {
          an[f] = *reinterpret_cast<const bf16x8*>(Ap + (size_t)k0 * NCOLP + (size_t)(f * 16) * 8);
          bn[f] = *reinterpret_cast<const bf16x8*>(Bp + (size_t)k0 * NCOLP + (size_t)(f * 16) * 8);
        }
      }
      #pragma unroll
      for (int fa = 0; fa < 4; ++fa)
        #pragma unroll
        for (int fc = 0; fc < 4; ++fc)
          acc[fa][fc] = __builtin_amdgcn_mfma_f32_16x16x32_bf16(a[fa], b[fc], acc[fa][fc], 0, 0, 0);
      if (more) {
        #pragma unroll
        for (int f = 0; f < 4; ++f) { a[f] = an[f]; b[f] = bn[f]; }
      }
    }
  }
  __syncthreads();   // tI tables ready for epilogue

  // ---- fused epilogue ----
  // C/D layout (m89-verified): Q(col) = lane&15, P(row) = (lane>>4)*4 + reg
  const float inv_cnt = 1.f / ((float)nb + 1e-7f);
  float sum = 0.f;
  #pragma unroll
  for (int fa = 0; fa < 4; ++fa) {
    #pragma unroll
    for (int r = 0; r < 4; ++r) {
      const int P = pb + fa * 16 + kg * 4 + r;
      const int i = tI0[P], j = tI1[P];
      #pragma unroll
      for (int fc = 0; fc < 4; ++fc) {
        const int Q = qb + fc * 16 + lr;
        const int li = tI0[Q], mi = tI1[Q];
        const float g = acc[fa][fc][r];
        if (P < NP) {
          if (Q < NP) {
            int s0 = min(i, li), x1 = max(i, li), x2 = min(j, mi), s3 = max(j, mi);
            int s1 = min(x1, x2), s2 = max(x1, x2);
            bool e01 = (s0 == s1), e12 = (s1 == s2), e23 = (s2 == s3);
            float wgt, tgt = 0.f;
            if (e01 && e12 && e23)                 wgt = 0.f;
            else if (e01 && e23)                   { wgt = 2.f / 9.f; tgt = T4C1; }
            else if ((e01 && e12) || (e12 && e23)) wgt = 0.25f;
            else if (e01 || e12 || e23)            wgt = 5.f / 24.f;
            else                                   wgt = 1.f / 6.f;
            float d = c4f(g) - tgt;
            sum += 0.125f * wgt * d * d;
          } else if (Q < 560) {
            if (Q - NP >= j) { float d = c3f(g); sum += 0.25f * d * d; }
          } else if (Q == 560) {
            if (i < j) { float d = c2f(g * inv_cnt); sum += 0.5f * d * d; }
          }
        } else if (P < 560 && Q == 560) {
          float m1 = g * inv_cnt;
          sum += m1 * m1;
        }
      }
    }
  }

  #pragma unroll
  for (int off = 32; off > 0; off >>= 1) sum += __shfl_down(sum, off, 64);
  if ((t & 63) == 0) sred[t >> 6] = sum;
  __syncthreads();
  if (t == 0) {
    float s = sred[0] + sred[1] + sred[2] + sred[3];
    atomicAdd(lossAcc, s * ((float)nb * (1.f / (float)B_N)));
    __threadfence();
    if (atomicAdd(ctr, 1) == NBLK - 1) out[0] = atomicAdd(lossAcc, 0.f);
  }
}

extern "C" void kernel_launch(void* const* d_in, const int* in_sizes, int n_in,
                              void* d_out, int out_size, void* d_ws, size_t ws_size,
                              hipStream_t stream) {
  const float* emb = (const float*)d_in[0];
  const float* cen = (const float*)d_in[1];
  const float* lg  = (const float*)d_in[2];
  float* out = (float*)d_out;

  int*   wsi    = (int*)d_ws;
  float* wsf    = (float*)d_ws;
  int*   cw     = wsi + WS_CW;
  int*   offp   = wsi + WS_OFFP;
  float* lossA  = wsf + WS_LOSS;
  int*   ctr    = wsi + WS_CTR;
  float* diffc  = wsf + WS_DIFFC;
  unsigned short* Vt = (unsigned short*)(wsf + WS_VT);

  k_prep  <<<1, 1024, 0, stream>>>(emb, cen, lg, cw, offp, diffc, lossA, ctr);
  k_expand<<<NR / 16, 256, 0, stream>>>(diffc, Vt);
  k_main  <<<dim3(NT, NT, K_N), 256, 0, stream>>>(Vt, cw, offp, lossA, ctr, out);
}